// Round 1
// baseline (974.562 us; speedup 1.0000x reference)
//
#include <hip/hip_runtime.h>
#include <hip/hip_bf16.h>

// Problem constants
#define BATCH 2
#define SEQ   4096
#define DIM   512
#define NHEAD 8
#define HDIM  64
#define HALF  256
#define ROWS  (BATCH*SEQ)   // 8192

typedef float  fx4   __attribute__((ext_vector_type(4)));
typedef __bf16 bf16x8 __attribute__((ext_vector_type(8)));
typedef unsigned short ushort_t;
typedef unsigned short usx4 __attribute__((ext_vector_type(4)));

static __device__ __forceinline__ float b2f(ushort_t v) {
    union { unsigned int u; float f; } c; c.u = ((unsigned int)v) << 16; return c.f;
}
static __device__ __forceinline__ ushort_t f2b(float f) {
    union { float f; unsigned int u; } c; c.f = f;
    unsigned int u = c.u;
    unsigned int r = (u + 0x7FFFu + ((u >> 16) & 1u)) >> 16;
    return (ushort_t)r;
}

// ---------------- prep: fp32 -> bf16 cast ----------------
__global__ __launch_bounds__(256) void cvt_bf16_kernel(const float* __restrict__ x,
                                                       ushort_t* __restrict__ y, int n) {
    int i = (blockIdx.x * 256 + threadIdx.x) * 4;
    if (i < n) {
        fx4 v = *(const fx4*)(x + i);
        usx4 o; o.x = f2b(v.x); o.y = f2b(v.y); o.z = f2b(v.z); o.w = f2b(v.w);
        *(usx4*)(y + i) = o;
    }
}

// ---------------- prep: transpose 512x512 fp32 -> bf16 (WT[n][k] = W[k][n]) ----------------
__global__ __launch_bounds__(256) void transpose_bf16_kernel(const float* __restrict__ W,
                                                             ushort_t* __restrict__ WT) {
    __shared__ float tile[64][65];
    int r0 = (blockIdx.x & 7) * 64;   // n-tile (rows of WT)
    int c0 = (blockIdx.x >> 3) * 64;  // k-tile (cols of WT)
    int tid = threadIdx.x;
    for (int idx = tid; idx < 4096; idx += 256) {
        int rr = idx >> 6, cc = idx & 63;
        tile[rr][cc] = W[(c0 + rr) * 512 + (r0 + cc)];   // coalesced read of W
    }
    __syncthreads();
    for (int idx = tid; idx < 4096; idx += 256) {
        int rr = idx >> 6, cc = idx & 63;
        WT[(size_t)(r0 + rr) * 512 + (c0 + cc)] = f2b(tile[cc][rr]);  // coalesced write of WT
    }
}

// ---------------- bf16 GEMM, C = A @ W + bias, with W^T supplied ----------------
// A: [M][512] bf16 row-major.  BT: [512][512] bf16 with BT[n][k] = W[k][n].
// grid: (M/64, 512/64, nmat). 256 threads = 4 waves, each wave does 16 rows x 64 cols.
__global__ __launch_bounds__(256) void gemm_bt_kernel(
    const ushort_t* __restrict__ A,
    const ushort_t* __restrict__ BT0, const ushort_t* __restrict__ BT1, const ushort_t* __restrict__ BT2,
    const float* __restrict__ b0, const float* __restrict__ b1, const float* __restrict__ b2,
    ushort_t* __restrict__ C0, ushort_t* __restrict__ C1, ushort_t* __restrict__ C2) {

    const ushort_t* BT; const float* bias; ushort_t* C;
    if (blockIdx.z == 0)      { BT = BT0; bias = b0; C = C0; }
    else if (blockIdx.z == 1) { BT = BT1; bias = b1; C = C1; }
    else                      { BT = BT2; bias = b2; C = C2; }

    int tid  = threadIdx.x;
    int wave = tid >> 6;
    int lane = tid & 63;
    int lm = lane & 15;       // m (A-frag) / n (B-frag) / col (C)
    int lq = lane >> 4;       // quad

    int m0 = blockIdx.x * 64 + wave * 16;
    int n0 = blockIdx.y * 64;

    const ushort_t* Arow = A  + (size_t)(m0 + lm) * 512 + lq * 8;
    const ushort_t* Brow = BT + (size_t)(n0 + lm) * 512 + lq * 8;

    fx4 acc[4];
    acc[0] = 0; acc[1] = 0; acc[2] = 0; acc[3] = 0;

    #pragma unroll
    for (int k0 = 0; k0 < 512; k0 += 32) {
        bf16x8 a = *(const bf16x8*)(Arow + k0);
        #pragma unroll
        for (int t = 0; t < 4; ++t) {
            bf16x8 b = *(const bf16x8*)(Brow + (size_t)t * 16 * 512 + k0);
            acc[t] = __builtin_amdgcn_mfma_f32_16x16x32_bf16(a, b, acc[t], 0, 0, 0);
        }
    }

    int mrow = m0 + lq * 4;   // C row = quad*4 + reg
    #pragma unroll
    for (int t = 0; t < 4; ++t) {
        int n = n0 + t * 16 + lm;   // C col = lane&15
        float bv = bias[n];
        #pragma unroll
        for (int r = 0; r < 4; ++r) {
            C[(size_t)(mrow + r) * 512 + n] = f2b(acc[t][r] + bv);
        }
    }
}

// ---------------- sliding-window attention (radius 256), fp32 VALU ----------------
// grid: (SEQ/128, BATCH*NHEAD), 128 threads. One thread per query.
__global__ __launch_bounds__(128) void attn_kernel(
    const ushort_t* __restrict__ Qb, const ushort_t* __restrict__ Kb,
    const ushort_t* __restrict__ Vb, ushort_t* __restrict__ Ob) {

    __shared__ float lk[64 * 64];
    __shared__ float lv[64 * 64];

    int tid  = threadIdx.x;
    int wave = tid >> 6;
    int bh = blockIdx.y;
    int b = bh >> 3, h = bh & 7;
    int q0 = blockIdx.x * 128;
    int q  = q0 + tid;

    // load this thread's query vector (64 bf16, contiguous)
    const ushort_t* qp = Qb + ((size_t)(b * SEQ + q)) * 512 + h * 64;
    fx4 qr[16];
    #pragma unroll
    for (int i = 0; i < 16; ++i) {
        usx4 u = ((const usx4*)qp)[i];
        fx4 v; v.x = b2f(u.x); v.y = b2f(u.y); v.z = b2f(u.z); v.w = b2f(u.w);
        qr[i] = v;
    }

    fx4 acc[16];
    #pragma unroll
    for (int i = 0; i < 16; ++i) acc[i] = 0;
    float l = 0.0f;

    int kstart = q0 - 256;
    for (int t = 0; t < 10; ++t) {
        int ts = kstart + t * 64;
        __syncthreads();  // protect previous tile
        for (int idx = tid; idx < 4096; idx += 128) {
            int j = idx >> 6, d = idx & 63;
            int g = ts + j;
            float kv = 0.0f, vv = 0.0f;
            if ((unsigned)g < (unsigned)SEQ) {
                size_t off = ((size_t)(b * SEQ + g)) * 512 + h * 64 + d;
                kv = b2f(Kb[off]);
                vv = b2f(Vb[off]);
            }
            lk[idx] = kv; lv[idx] = vv;
        }
        __syncthreads();

        // wave w covers queries [q0+64w, q0+64w+63]; its window only touches tiles t in [w, w+8]
        if (t >= wave && t <= wave + 8 && ts < SEQ && ts + 64 > 0) {
            for (int j = 0; j < 64; ++j) {
                int g = ts + j;
                const fx4* kj = (const fx4*)(lk + j * 64);
                fx4 s4 = 0;
                #pragma unroll
                for (int i = 0; i < 16; ++i) s4 += qr[i] * kj[i];
                float s = (s4.x + s4.y + s4.z + s4.w) * 0.125f;
                bool valid = ((unsigned)g < (unsigned)SEQ) && (g - q <= 256) && (q - g <= 256);
                float p = valid ? __expf(s) : 0.0f;
                l += p;
                const fx4* vj = (const fx4*)(lv + j * 64);
                #pragma unroll
                for (int i = 0; i < 16; ++i) acc[i] += p * vj[i];
            }
        }
    }

    float inv = 1.0f / l;
    ushort_t* op = Ob + ((size_t)(b * SEQ + q)) * 512 + h * 64;
    #pragma unroll
    for (int i = 0; i < 16; ++i) {
        fx4 v = acc[i] * inv;
        usx4 o; o.x = f2b(v.x); o.y = f2b(v.y); o.z = f2b(v.z); o.w = f2b(v.w);
        ((usx4*)op)[i] = o;
    }
}

// ---------------- residual + LayerNorm ----------------
// grid: ROWS/4 blocks, 256 threads = 4 waves, one wave per row. lane handles 8 cols.
__global__ __launch_bounds__(256) void ln_kernel(
    const float* __restrict__ x, const ushort_t* __restrict__ ob,
    const float* __restrict__ gamma, const float* __restrict__ beta,
    float* __restrict__ out) {

    int row  = blockIdx.x * 4 + (threadIdx.x >> 6);
    int lane = threadIdx.x & 63;

    const float*    xp = x  + (size_t)row * 512 + lane * 8;
    const ushort_t* op = ob + (size_t)row * 512 + lane * 8;

    fx4 xa = ((const fx4*)xp)[0];
    fx4 xb = ((const fx4*)xp)[1];
    usx4 oa = ((const usx4*)op)[0];
    usx4 oc = ((const usx4*)op)[1];
    fx4 va, vb;
    va.x = xa.x + b2f(oa.x); va.y = xa.y + b2f(oa.y); va.z = xa.z + b2f(oa.z); va.w = xa.w + b2f(oa.w);
    vb.x = xb.x + b2f(oc.x); vb.y = xb.y + b2f(oc.y); vb.z = xb.z + b2f(oc.z); vb.w = xb.w + b2f(oc.w);

    float s = va.x + va.y + va.z + va.w + vb.x + vb.y + vb.z + vb.w;
    #pragma unroll
    for (int m = 32; m > 0; m >>= 1) s += __shfl_xor(s, m);
    float mu = s * (1.0f / 512.0f);

    fx4 da = va - mu;
    fx4 db = vb - mu;
    float ss = da.x*da.x + da.y*da.y + da.z*da.z + da.w*da.w
             + db.x*db.x + db.y*db.y + db.z*db.z + db.w*db.w;
    #pragma unroll
    for (int m = 32; m > 0; m >>= 1) ss += __shfl_xor(ss, m);
    float rstd = rsqrtf(ss * (1.0f / 512.0f) + 1e-5f);

    const fx4* gp = (const fx4*)(gamma + lane * 8);
    const fx4* bp = (const fx4*)(beta  + lane * 8);
    fx4 g0 = gp[0], g1 = gp[1], b0 = bp[0], b1 = bp[1];

    float* outp = out + (size_t)row * 512 + lane * 8;
    fx4 r0 = da * rstd * g0 + b0;
    fx4 r1 = db * rstd * g1 + b1;
    ((fx4*)outp)[0] = r0;
    ((fx4*)outp)[1] = r1;
}

extern "C" void kernel_launch(void* const* d_in, const int* in_sizes, int n_in,
                              void* d_out, int out_size, void* d_ws, size_t ws_size,
                              hipStream_t stream) {
    const float* val   = (const float*)d_in[0];
    const float* Wq    = (const float*)d_in[1];
    const float* bq    = (const float*)d_in[2];
    const float* Wk    = (const float*)d_in[3];
    const float* bk    = (const float*)d_in[4];
    const float* Wv    = (const float*)d_in[5];
    const float* bv    = (const float*)d_in[6];
    const float* Wo    = (const float*)d_in[7];
    const float* bo    = (const float*)d_in[8];
    const float* gamma = (const float*)d_in[9];
    const float* beta  = (const float*)d_in[10];
    float* out = (float*)d_out;

    // workspace layout
    char* w = (char*)d_ws;
    ushort_t* xb    = (ushort_t*)w; w += (size_t)ROWS * 512 * 2;   // 8 MB
    ushort_t* WqT   = (ushort_t*)w; w += 512 * 512 * 2;
    ushort_t* WkT   = (ushort_t*)w; w += 512 * 512 * 2;
    ushort_t* WvT   = (ushort_t*)w; w += 512 * 512 * 2;
    ushort_t* WoT   = (ushort_t*)w; w += 512 * 512 * 2;
    ushort_t* Qb    = (ushort_t*)w; w += (size_t)ROWS * 512 * 2;
    ushort_t* Kb    = (ushort_t*)w; w += (size_t)ROWS * 512 * 2;
    ushort_t* Vb    = (ushort_t*)w; w += (size_t)ROWS * 512 * 2;
    ushort_t* attnb = (ushort_t*)w; w += (size_t)ROWS * 512 * 2;
    ushort_t* obuf  = (ushort_t*)w; w += (size_t)ROWS * 512 * 2;

    int nelem = ROWS * 512;  // 4194304
    cvt_bf16_kernel<<<nelem / (256 * 4), 256, 0, stream>>>(val, xb, nelem);
    transpose_bf16_kernel<<<64, 256, 0, stream>>>(Wq, WqT);
    transpose_bf16_kernel<<<64, 256, 0, stream>>>(Wk, WkT);
    transpose_bf16_kernel<<<64, 256, 0, stream>>>(Wv, WvT);
    transpose_bf16_kernel<<<64, 256, 0, stream>>>(Wo, WoT);

    gemm_bt_kernel<<<dim3(ROWS / 64, 8, 3), 256, 0, stream>>>(
        xb, WqT, WkT, WvT, bq, bk, bv, Qb, Kb, Vb);

    attn_kernel<<<dim3(SEQ / 128, BATCH * NHEAD), 128, 0, stream>>>(Qb, Kb, Vb, attnb);

    gemm_bt_kernel<<<dim3(ROWS / 64, 8, 1), 256, 0, stream>>>(
        attnb, WoT, WoT, WoT, bo, bo, bo, obuf, obuf, obuf);

    ln_kernel<<<ROWS / 4, 256, 0, stream>>>(val, obuf, gamma, beta, out);
}

// Round 2
// 294.113 us; speedup vs baseline: 3.3136x; 3.3136x over previous
//
#include <hip/hip_runtime.h>
#include <hip/hip_bf16.h>

// Problem constants
#define BATCH 2
#define SEQ   4096
#define DIM   512
#define NHEAD 8
#define HDIM  64
#define ROWS  (BATCH*SEQ)   // 8192

typedef float  fx4   __attribute__((ext_vector_type(4)));
typedef __bf16 bf16x8 __attribute__((ext_vector_type(8)));
typedef unsigned short ushort_t;
typedef unsigned short usx4 __attribute__((ext_vector_type(4)));
typedef unsigned short usx8 __attribute__((ext_vector_type(8)));

static __device__ __forceinline__ float b2f(ushort_t v) {
    union { unsigned int u; float f; } c; c.u = ((unsigned int)v) << 16; return c.f;
}
static __device__ __forceinline__ ushort_t f2b(float f) {
    union { float f; unsigned int u; } c; c.f = f;
    unsigned int u = c.u;
    unsigned int r = (u + 0x7FFFu + ((u >> 16) & 1u)) >> 16;
    return (ushort_t)r;
}

// ---------------- prep: fp32 -> bf16 cast ----------------
__global__ __launch_bounds__(256) void cvt_bf16_kernel(const float* __restrict__ x,
                                                       ushort_t* __restrict__ y, int n) {
    int i = (blockIdx.x * 256 + threadIdx.x) * 4;
    if (i < n) {
        fx4 v = *(const fx4*)(x + i);
        usx4 o; o.x = f2b(v.x); o.y = f2b(v.y); o.z = f2b(v.z); o.w = f2b(v.w);
        *(usx4*)(y + i) = o;
    }
}

// ---------------- prep: transpose 512x512 fp32 -> bf16 (WT[n][k] = W[k][n]) ----------------
__global__ __launch_bounds__(256) void transpose_bf16_kernel(const float* __restrict__ W,
                                                             ushort_t* __restrict__ WT) {
    __shared__ float tile[64][65];
    int r0 = (blockIdx.x & 7) * 64;   // n-tile (rows of WT)
    int c0 = (blockIdx.x >> 3) * 64;  // k-tile (cols of WT)
    int tid = threadIdx.x;
    for (int idx = tid; idx < 4096; idx += 256) {
        int rr = idx >> 6, cc = idx & 63;
        tile[rr][cc] = W[(c0 + rr) * 512 + (r0 + cc)];   // coalesced read of W
    }
    __syncthreads();
    for (int idx = tid; idx < 4096; idx += 256) {
        int rr = idx >> 6, cc = idx & 63;
        WT[(size_t)(r0 + rr) * 512 + (c0 + cc)] = f2b(tile[cc][rr]);  // coalesced write of WT
    }
}

// ---------------- bf16 GEMM, C = A @ W + bias, with W^T supplied ----------------
// A: [M][512] bf16 row-major.  BT: [512][512] bf16 with BT[n][k] = W[k][n].
// grid: (M/64, 512/64, nmat). 256 threads = 4 waves, each wave does 16 rows x 64 cols.
// z==2 writes the output TRANSPOSED per head: Vt[((b*8+h)*64+d)*4096 + s]
__global__ __launch_bounds__(256) void gemm_bt_kernel(
    const ushort_t* __restrict__ A,
    const ushort_t* __restrict__ BT0, const ushort_t* __restrict__ BT1, const ushort_t* __restrict__ BT2,
    const float* __restrict__ b0, const float* __restrict__ b1, const float* __restrict__ b2,
    ushort_t* __restrict__ C0, ushort_t* __restrict__ C1, ushort_t* __restrict__ C2) {

    const ushort_t* BT; const float* bias; ushort_t* C;
    if (blockIdx.z == 0)      { BT = BT0; bias = b0; C = C0; }
    else if (blockIdx.z == 1) { BT = BT1; bias = b1; C = C1; }
    else                      { BT = BT2; bias = b2; C = C2; }

    int tid  = threadIdx.x;
    int wave = tid >> 6;
    int lane = tid & 63;
    int lm = lane & 15;       // m (A-frag) / n (B-frag) / col (C)
    int lq = lane >> 4;       // quad

    int m0 = blockIdx.x * 64 + wave * 16;
    int n0 = blockIdx.y * 64;

    const ushort_t* Arow = A  + (size_t)(m0 + lm) * 512 + lq * 8;
    const ushort_t* Brow = BT + (size_t)(n0 + lm) * 512 + lq * 8;

    fx4 acc[4];
    acc[0] = 0; acc[1] = 0; acc[2] = 0; acc[3] = 0;

    #pragma unroll
    for (int k0 = 0; k0 < 512; k0 += 32) {
        bf16x8 a = *(const bf16x8*)(Arow + k0);
        #pragma unroll
        for (int t = 0; t < 4; ++t) {
            bf16x8 b = *(const bf16x8*)(Brow + (size_t)t * 16 * 512 + k0);
            acc[t] = __builtin_amdgcn_mfma_f32_16x16x32_bf16(a, b, acc[t], 0, 0, 0);
        }
    }

    int mrow = m0 + lq * 4;   // C row = quad*4 + reg
    if (blockIdx.z == 2) {
        // transposed per-head write: Vt[bh][d][s], 4 consecutive s per lane -> 8B store
        int bq_ = mrow >> 12;         // batch
        int s0  = mrow & 4095;        // seq pos of reg 0
        #pragma unroll
        for (int t = 0; t < 4; ++t) {
            int n = n0 + t * 16 + lm;
            int h = n >> 6, d = n & 63;
            float bv = bias[n];
            usx4 o;
            o.x = f2b(acc[t][0] + bv); o.y = f2b(acc[t][1] + bv);
            o.z = f2b(acc[t][2] + bv); o.w = f2b(acc[t][3] + bv);
            *(usx4*)(C + (((size_t)(bq_ * 8 + h) * 64 + d) * 4096 + s0)) = o;
        }
    } else {
        #pragma unroll
        for (int t = 0; t < 4; ++t) {
            int n = n0 + t * 16 + lm;
            float bv = bias[n];
            #pragma unroll
            for (int r = 0; r < 4; ++r) {
                C[(size_t)(mrow + r) * 512 + n] = f2b(acc[t][r] + bv);
            }
        }
    }
}

// ---------------- MFMA sliding-window attention (radius 256) ----------------
// grid: (SEQ/64, BATCH*NHEAD), 256 threads = 4 waves, wave handles 16 queries.
// Qb,Kb: [b][s][h*64+d] bf16.  Vt: [bh][d][s] bf16.  Ob: [b][s][h*64+d] bf16.
// LDS tiles are XOR-swizzled in 16B granules: element(row,col) lives at
//   row*64 + ((col>>3) ^ swz(row))*8 + (col&7)
__global__ __launch_bounds__(256) void attn_mfma_kernel(
    const ushort_t* __restrict__ Qb, const ushort_t* __restrict__ Kb,
    const ushort_t* __restrict__ Vt, ushort_t* __restrict__ Ob) {

    __shared__ ushort_t Klds[64 * 64];   // [key][d], swz(row)=row&7
    __shared__ ushort_t Vlds[64 * 64];   // [d][key], swz(row)=row&7
    __shared__ ushort_t Plds[4 * 16 * 64]; // per-wave [q][key], swz(row)=(row&7)^((row>>3)<<1)

    const int tid  = threadIdx.x;
    const int wave = tid >> 6;
    const int lane = tid & 63;
    const int lm   = lane & 15;
    const int quad = lane >> 4;

    const int bh = blockIdx.y;
    const int b = bh >> 3, h = bh & 7;
    const int q0 = blockIdx.x * 64;
    const int qw = q0 + wave * 16;

    // preload Q A-fragments (16 queries x 64 d)
    const ushort_t* qp = Qb + ((size_t)(b * SEQ + qw + lm)) * 512 + h * 64 + quad * 8;
    bf16x8 qf0 = *(const bf16x8*)qp;          // d = quad*8 + 0..7
    bf16x8 qf1 = *(const bf16x8*)(qp + 32);   // d = 32 + quad*8 + 0..7

    // precompute LDS element offsets (kt-invariant)
    int koff[2][4], voff[2][4];
    #pragma unroll
    for (int ks = 0; ks < 2; ++ks) {
        #pragma unroll
        for (int tn = 0; tn < 4; ++tn) {
            int key = tn * 16 + lm;   // K B-frag: n=key
            koff[ks][tn] = key * 64 + (((ks * 4 + quad) ^ (key & 7)) * 8);
            int d = tn * 16 + lm;     // V B-frag: n=d
            voff[ks][tn] = d * 64 + (((ks * 4 + quad) ^ (d & 7)) * 8);
        }
    }
    int poff[2];
    #pragma unroll
    for (int ks = 0; ks < 2; ++ks)
        poff[ks] = lm * 64 + (((ks * 4 + quad) ^ (lm & 7) ^ ((lm >> 3) << 1)) * 8);
    int pwoff[4][4];
    #pragma unroll
    for (int tn = 0; tn < 4; ++tn) {
        #pragma unroll
        for (int r = 0; r < 4; ++r) {
            int row = quad * 4 + r;
            int col = tn * 16 + lm;
            pwoff[tn][r] = row * 64 + (((col >> 3) ^ (row & 7) ^ ((row >> 3) << 1)) * 8) + (col & 7);
        }
    }
    ushort_t* Pl = Plds + wave * 1024;

    // staging addressing: thread loads 2x16B for K and 2x16B for V per tile
    const int skey = tid >> 3;   // 0..31 (row for K tile / d-row for V tile)
    const int sdg  = tid & 7;    // 16B granule within row
    const size_t kgbase = ((size_t)b * SEQ) * 512 + h * 64 + sdg * 8;
    const size_t vgbase = ((size_t)bh * 64) * 4096 + sdg * 8;
    const int l0 = skey * 64 + ((sdg ^ (skey & 7)) * 8);
    const int l1 = l0 + 32 * 64;   // (skey+32)&7 == skey&7

    fx4 oacc[4];
    oacc[0] = 0; oacc[1] = 0; oacc[2] = 0; oacc[3] = 0;
    float l[4] = {0.f, 0.f, 0.f, 0.f};

    for (int kt = 0; kt < 9; ++kt) {
        int ts = q0 - 256 + kt * 64;
        if (ts < 0 || ts >= SEQ) continue;   // block-uniform

        __syncthreads();
        {
            usx8 k0v = *(const usx8*)(Kb + kgbase + (size_t)(ts + skey) * 512);
            usx8 k1v = *(const usx8*)(Kb + kgbase + (size_t)(ts + skey + 32) * 512);
            usx8 v0v = *(const usx8*)(Vt + vgbase + (size_t)skey * 4096 + ts);
            usx8 v1v = *(const usx8*)(Vt + vgbase + (size_t)(skey + 32) * 4096 + ts);
            *(usx8*)&Klds[l0] = k0v;
            *(usx8*)&Klds[l1] = k1v;
            *(usx8*)&Vlds[l0] = v0v;
            *(usx8*)&Vlds[l1] = v1v;
        }
        __syncthreads();

        // S = Q (16x64) @ K^T (64 keys)
        fx4 sacc[4];
        sacc[0] = 0; sacc[1] = 0; sacc[2] = 0; sacc[3] = 0;
        #pragma unroll
        for (int ks = 0; ks < 2; ++ks) {
            bf16x8 a = ks ? qf1 : qf0;
            #pragma unroll
            for (int tn = 0; tn < 4; ++tn) {
                bf16x8 bk = *(const bf16x8*)&Klds[koff[ks][tn]];
                sacc[tn] = __builtin_amdgcn_mfma_f32_16x16x32_bf16(a, bk, sacc[tn], 0, 0, 0);
            }
        }

        // band mask + exp; write P to per-wave LDS; accumulate row sums
        float ps[4] = {0.f, 0.f, 0.f, 0.f};
        #pragma unroll
        for (int tn = 0; tn < 4; ++tn) {
            int kg = ts + tn * 16 + lm;
            #pragma unroll
            for (int r = 0; r < 4; ++r) {
                int qg = qw + quad * 4 + r;
                int dlt = kg - qg;
                float p = (dlt <= 256 && dlt >= -256) ? __expf(sacc[tn][r] * 0.125f) : 0.0f;
                ps[r] += p;
                Pl[pwoff[tn][r]] = f2b(p);
            }
        }
        #pragma unroll
        for (int r = 0; r < 4; ++r) {
            float v = ps[r];
            v += __shfl_xor(v, 1); v += __shfl_xor(v, 2);
            v += __shfl_xor(v, 4); v += __shfl_xor(v, 8);
            l[r] += v;
        }

        // O += P (16x64) @ V (64 keys x 64 d)
        #pragma unroll
        for (int ks = 0; ks < 2; ++ks) {
            bf16x8 ap = *(const bf16x8*)&Pl[poff[ks]];
            #pragma unroll
            for (int tn = 0; tn < 4; ++tn) {
                bf16x8 bv = *(const bf16x8*)&Vlds[voff[ks][tn]];
                oacc[tn] = __builtin_amdgcn_mfma_f32_16x16x32_bf16(ap, bv, oacc[tn], 0, 0, 0);
            }
        }
    }

    // normalize + write out (C-layout: row = quad*4 + r, col = tn*16 + lm)
    #pragma unroll
    for (int r = 0; r < 4; ++r) l[r] = 1.0f / l[r];
    ushort_t* ob = Ob + ((size_t)(b * SEQ + qw + quad * 4)) * 512 + h * 64 + lm;
    #pragma unroll
    for (int tn = 0; tn < 4; ++tn) {
        #pragma unroll
        for (int r = 0; r < 4; ++r) {
            ob[(size_t)r * 512 + tn * 16] = f2b(oacc[tn][r] * l[r]);
        }
    }
}

// ---------------- residual + LayerNorm ----------------
__global__ __launch_bounds__(256) void ln_kernel(
    const float* __restrict__ x, const ushort_t* __restrict__ ob,
    const float* __restrict__ gamma, const float* __restrict__ beta,
    float* __restrict__ out) {

    int row  = blockIdx.x * 4 + (threadIdx.x >> 6);
    int lane = threadIdx.x & 63;

    const float*    xp = x  + (size_t)row * 512 + lane * 8;
    const ushort_t* op = ob + (size_t)row * 512 + lane * 8;

    fx4 xa = ((const fx4*)xp)[0];
    fx4 xb = ((const fx4*)xp)[1];
    usx4 oa = ((const usx4*)op)[0];
    usx4 oc = ((const usx4*)op)[1];
    fx4 va, vb;
    va.x = xa.x + b2f(oa.x); va.y = xa.y + b2f(oa.y); va.z = xa.z + b2f(oa.z); va.w = xa.w + b2f(oa.w);
    vb.x = xb.x + b2f(oc.x); vb.y = xb.y + b2f(oc.y); vb.z = xb.z + b2f(oc.z); vb.w = xb.w + b2f(oc.w);

    float s = va.x + va.y + va.z + va.w + vb.x + vb.y + vb.z + vb.w;
    #pragma unroll
    for (int m = 32; m > 0; m >>= 1) s += __shfl_xor(s, m);
    float mu = s * (1.0f / 512.0f);

    fx4 da = va - mu;
    fx4 db = vb - mu;
    float ss = da.x*da.x + da.y*da.y + da.z*da.z + da.w*da.w
             + db.x*db.x + db.y*db.y + db.z*db.z + db.w*db.w;
    #pragma unroll
    for (int m = 32; m > 0; m >>= 1) ss += __shfl_xor(ss, m);
    float rstd = rsqrtf(ss * (1.0f / 512.0f) + 1e-5f);

    const fx4* gp = (const fx4*)(gamma + lane * 8);
    const fx4* bp = (const fx4*)(beta  + lane * 8);
    fx4 g0 = gp[0], g1 = gp[1], b0 = bp[0], b1 = bp[1];

    float* outp = out + (size_t)row * 512 + lane * 8;
    fx4 r0 = da * rstd * g0 + b0;
    fx4 r1 = db * rstd * g1 + b1;
    ((fx4*)outp)[0] = r0;
    ((fx4*)outp)[1] = r1;
}

extern "C" void kernel_launch(void* const* d_in, const int* in_sizes, int n_in,
                              void* d_out, int out_size, void* d_ws, size_t ws_size,
                              hipStream_t stream) {
    const float* val   = (const float*)d_in[0];
    const float* Wq    = (const float*)d_in[1];
    const float* bq    = (const float*)d_in[2];
    const float* Wk    = (const float*)d_in[3];
    const float* bk    = (const float*)d_in[4];
    const float* Wv    = (const float*)d_in[5];
    const float* bv    = (const float*)d_in[6];
    const float* Wo    = (const float*)d_in[7];
    const float* bo    = (const float*)d_in[8];
    const float* gamma = (const float*)d_in[9];
    const float* beta  = (const float*)d_in[10];
    float* out = (float*)d_out;

    // workspace layout
    char* w = (char*)d_ws;
    ushort_t* xb    = (ushort_t*)w; w += (size_t)ROWS * 512 * 2;   // 8 MB
    ushort_t* WqT   = (ushort_t*)w; w += 512 * 512 * 2;
    ushort_t* WkT   = (ushort_t*)w; w += 512 * 512 * 2;
    ushort_t* WvT   = (ushort_t*)w; w += 512 * 512 * 2;
    ushort_t* WoT   = (ushort_t*)w; w += 512 * 512 * 2;
    ushort_t* Qb    = (ushort_t*)w; w += (size_t)ROWS * 512 * 2;
    ushort_t* Kb    = (ushort_t*)w; w += (size_t)ROWS * 512 * 2;
    ushort_t* Vtb   = (ushort_t*)w; w += (size_t)ROWS * 512 * 2;   // [bh][d][s]
    ushort_t* attnb = (ushort_t*)w; w += (size_t)ROWS * 512 * 2;
    ushort_t* obuf  = (ushort_t*)w; w += (size_t)ROWS * 512 * 2;

    int nelem = ROWS * 512;  // 4194304
    cvt_bf16_kernel<<<nelem / (256 * 4), 256, 0, stream>>>(val, xb, nelem);
    transpose_bf16_kernel<<<64, 256, 0, stream>>>(Wq, WqT);
    transpose_bf16_kernel<<<64, 256, 0, stream>>>(Wk, WkT);
    transpose_bf16_kernel<<<64, 256, 0, stream>>>(Wv, WvT);
    transpose_bf16_kernel<<<64, 256, 0, stream>>>(Wo, WoT);

    gemm_bt_kernel<<<dim3(ROWS / 64, 8, 3), 256, 0, stream>>>(
        xb, WqT, WkT, WvT, bq, bk, bv, Qb, Kb, Vtb);

    attn_mfma_kernel<<<dim3(SEQ / 64, BATCH * NHEAD), 256, 0, stream>>>(Qb, Kb, Vtb, attnb);

    gemm_bt_kernel<<<dim3(ROWS / 64, 8, 1), 256, 0, stream>>>(
        attnb, WoT, WoT, WoT, bo, bo, bo, obuf, obuf, obuf);

    ln_kernel<<<ROWS / 4, 256, 0, stream>>>(val, obuf, gamma, beta, out);
}

// Round 3
// 169.563 us; speedup vs baseline: 5.7475x; 1.7345x over previous
//
#include <hip/hip_runtime.h>
#include <hip/hip_bf16.h>

// Problem constants
#define BATCH 2
#define SEQ   4096
#define DIM   512
#define NHEAD 8
#define HDIM  64
#define ROWS  (BATCH*SEQ)   // 8192

typedef float  fx4   __attribute__((ext_vector_type(4)));
typedef __bf16 bf16x8 __attribute__((ext_vector_type(8)));
typedef unsigned short ushort_t;
typedef unsigned short usx4 __attribute__((ext_vector_type(4)));
typedef unsigned short usx8 __attribute__((ext_vector_type(8)));

static __device__ __forceinline__ float b2f(ushort_t v) {
    union { unsigned int u; float f; } c; c.u = ((unsigned int)v) << 16; return c.f;
}
static __device__ __forceinline__ ushort_t f2b(float f) {
    union { float f; unsigned int u; } c; c.f = f;
    unsigned int u = c.u;
    unsigned int r = (u + 0x7FFFu + ((u >> 16) & 1u)) >> 16;
    return (ushort_t)r;
}
static __device__ __forceinline__ void gload16(const ushort_t* g, ushort_t* l) {
    __builtin_amdgcn_global_load_lds(
        (const __attribute__((address_space(1))) unsigned int*)g,
        (__attribute__((address_space(3))) unsigned int*)l, 16, 0, 0);
}

// ---------------- prep: fp32 -> bf16 cast ----------------
__global__ __launch_bounds__(256) void cvt_bf16_kernel(const float* __restrict__ x,
                                                       ushort_t* __restrict__ y, int n) {
    int i = (blockIdx.x * 256 + threadIdx.x) * 4;
    if (i < n) {
        fx4 v = *(const fx4*)(x + i);
        usx4 o; o.x = f2b(v.x); o.y = f2b(v.y); o.z = f2b(v.z); o.w = f2b(v.w);
        *(usx4*)(y + i) = o;
    }
}

// ---------------- prep: 4x transpose 512x512 fp32 -> bf16 (WT[n][k]=W[k][n]) ----------------
__global__ __launch_bounds__(256) void transpose4_bf16_kernel(
    const float* __restrict__ W0, const float* __restrict__ W1,
    const float* __restrict__ W2, const float* __restrict__ W3,
    ushort_t* __restrict__ T0, ushort_t* __restrict__ T1,
    ushort_t* __restrict__ T2, ushort_t* __restrict__ T3) {
    const float* W; ushort_t* WT;
    switch (blockIdx.y) {
        case 0: W = W0; WT = T0; break;
        case 1: W = W1; WT = T1; break;
        case 2: W = W2; WT = T2; break;
        default: W = W3; WT = T3; break;
    }
    __shared__ float tile[64][65];
    int r0 = (blockIdx.x & 7) * 64;
    int c0 = (blockIdx.x >> 3) * 64;
    int tid = threadIdx.x;
    for (int idx = tid; idx < 4096; idx += 256) {
        int rr = idx >> 6, cc = idx & 63;
        tile[rr][cc] = W[(c0 + rr) * 512 + (r0 + cc)];
    }
    __syncthreads();
    for (int idx = tid; idx < 4096; idx += 256) {
        int rr = idx >> 6, cc = idx & 63;
        WT[(size_t)(r0 + rr) * 512 + (c0 + cc)] = f2b(tile[cc][rr]);
    }
}

// ---------------- bf16 GEMM (m97 structure): C = A @ W + bias, W^T supplied ----------------
// 128x128 block tile, BK=32, global_load_lds(16B) staging, 4 waves in 2x2,
// each wave 64x64 = 4x4 MFMA 16x16x32 tiles.
// grid: (M/128, 512/128, nmat). z==2 writes transposed per head: Vt[bh][d][s].
__global__ __launch_bounds__(256) void gemm128_kernel(
    const ushort_t* __restrict__ A,
    const ushort_t* __restrict__ BT0, const ushort_t* __restrict__ BT1, const ushort_t* __restrict__ BT2,
    const float* __restrict__ b0, const float* __restrict__ b1, const float* __restrict__ b2,
    ushort_t* __restrict__ C0, ushort_t* __restrict__ C1, ushort_t* __restrict__ C2) {

    const ushort_t* BT; const float* bias; ushort_t* C;
    if (blockIdx.z == 0)      { BT = BT0; bias = b0; C = C0; }
    else if (blockIdx.z == 1) { BT = BT1; bias = b1; C = C1; }
    else                      { BT = BT2; bias = b2; C = C2; }

    __shared__ ushort_t As[128 * 32];
    __shared__ ushort_t Bs[128 * 32];

    const int tid  = threadIdx.x;
    const int wave = tid >> 6;
    const int lane = tid & 63;
    const int lm   = lane & 15;
    const int quad = lane >> 4;
    const int wm   = wave >> 1;
    const int wn   = wave & 1;

    const int m0t = blockIdx.x * 128;
    const int n0t = blockIdx.y * 128;

    // staging: granule g=tid covers (row=g>>2, 16B granule g&3); second batch row+64
    const int srow = tid >> 2, sgc = tid & 3;
    const ushort_t* ga0 = A  + (size_t)(m0t + srow) * 512 + sgc * 8;
    const ushort_t* ga1 = A  + (size_t)(m0t + srow + 64) * 512 + sgc * 8;
    const ushort_t* gb0 = BT + (size_t)(n0t + srow) * 512 + sgc * 8;
    const ushort_t* gb1 = BT + (size_t)(n0t + srow + 64) * 512 + sgc * 8;
    ushort_t* la0 = As + tid * 8;
    ushort_t* la1 = As + (tid + 256) * 8;
    ushort_t* lb0 = Bs + tid * 8;
    ushort_t* lb1 = Bs + (tid + 256) * 8;

    // fragment LDS offsets (ushort idx); + ms*16*32 per subtile
    const int aoff = (wm * 64 + lm) * 32 + quad * 8;
    const int boff = (wn * 64 + lm) * 32 + quad * 8;

    fx4 acc[4][4];
    #pragma unroll
    for (int i = 0; i < 4; ++i)
        #pragma unroll
        for (int j = 0; j < 4; ++j) acc[i][j] = 0;

    for (int k0 = 0; k0 < 512; k0 += 32) {
        __syncthreads();
        gload16(ga0 + k0, la0);
        gload16(ga1 + k0, la1);
        gload16(gb0 + k0, lb0);
        gload16(gb1 + k0, lb1);
        __syncthreads();

        bf16x8 af[4], bfr[4];
        #pragma unroll
        for (int ms = 0; ms < 4; ++ms) af[ms]  = *(const bf16x8*)&As[aoff + ms * 512];
        #pragma unroll
        for (int ns = 0; ns < 4; ++ns) bfr[ns] = *(const bf16x8*)&Bs[boff + ns * 512];
        #pragma unroll
        for (int ms = 0; ms < 4; ++ms)
            #pragma unroll
            for (int ns = 0; ns < 4; ++ns)
                acc[ms][ns] = __builtin_amdgcn_mfma_f32_16x16x32_bf16(af[ms], bfr[ns], acc[ms][ns], 0, 0, 0);
    }

    const int crow0 = m0t + wm * 64 + quad * 4;   // + ms*16 + r
    const int ccol0 = n0t + wn * 64 + lm;         // + ns*16

    if (blockIdx.z == 2) {
        // V: transposed per-head write Vt[((b*8+h)*64+d)*4096 + s]
        #pragma unroll
        for (int ns = 0; ns < 4; ++ns) {
            int col = ccol0 + ns * 16;
            int h = col >> 6, d = col & 63;
            float bv = bias[col];
            #pragma unroll
            for (int ms = 0; ms < 4; ++ms) {
                int m = crow0 + ms * 16;
                int bb = m >> 12, s0 = m & 4095;
                usx4 o;
                o.x = f2b(acc[ms][ns][0] + bv); o.y = f2b(acc[ms][ns][1] + bv);
                o.z = f2b(acc[ms][ns][2] + bv); o.w = f2b(acc[ms][ns][3] + bv);
                *(usx4*)(C + (((size_t)(bb * 8 + h) * 64 + d) * 4096 + s0)) = o;
            }
        }
    } else {
        #pragma unroll
        for (int ns = 0; ns < 4; ++ns) {
            int col = ccol0 + ns * 16;
            float bv = bias[col];
            #pragma unroll
            for (int ms = 0; ms < 4; ++ms) {
                #pragma unroll
                for (int r = 0; r < 4; ++r) {
                    C[(size_t)(crow0 + ms * 16 + r) * 512 + col] = f2b(acc[ms][ns][r] + bv);
                }
            }
        }
    }
}

// ---------------- MFMA sliding-window attention (radius 256) ----------------
// grid: (SEQ/64, BATCH*NHEAD), 256 threads = 4 waves, wave handles 16 queries.
__global__ __launch_bounds__(256) void attn_mfma_kernel(
    const ushort_t* __restrict__ Qb, const ushort_t* __restrict__ Kb,
    const ushort_t* __restrict__ Vt, ushort_t* __restrict__ Ob) {

    __shared__ ushort_t Klds[64 * 64];
    __shared__ ushort_t Vlds[64 * 64];
    __shared__ ushort_t Plds[4 * 16 * 64];

    const int tid  = threadIdx.x;
    const int wave = tid >> 6;
    const int lane = tid & 63;
    const int lm   = lane & 15;
    const int quad = lane >> 4;

    const int bh = blockIdx.y;
    const int b = bh >> 3, h = bh & 7;
    const int q0 = blockIdx.x * 64;
    const int qw = q0 + wave * 16;

    const ushort_t* qp = Qb + ((size_t)(b * SEQ + qw + lm)) * 512 + h * 64 + quad * 8;
    bf16x8 qf0 = *(const bf16x8*)qp;
    bf16x8 qf1 = *(const bf16x8*)(qp + 32);

    int koff[2][4], voff[2][4];
    #pragma unroll
    for (int ks = 0; ks < 2; ++ks) {
        #pragma unroll
        for (int tn = 0; tn < 4; ++tn) {
            int key = tn * 16 + lm;
            koff[ks][tn] = key * 64 + (((ks * 4 + quad) ^ (key & 7)) * 8);
            int d = tn * 16 + lm;
            voff[ks][tn] = d * 64 + (((ks * 4 + quad) ^ (d & 7)) * 8);
        }
    }
    int poff[2];
    #pragma unroll
    for (int ks = 0; ks < 2; ++ks)
        poff[ks] = lm * 64 + (((ks * 4 + quad) ^ (lm & 7) ^ ((lm >> 3) << 1)) * 8);
    int pwoff[4][4];
    #pragma unroll
    for (int tn = 0; tn < 4; ++tn) {
        #pragma unroll
        for (int r = 0; r < 4; ++r) {
            int row = quad * 4 + r;
            int col = tn * 16 + lm;
            pwoff[tn][r] = row * 64 + (((col >> 3) ^ (row & 7) ^ ((row >> 3) << 1)) * 8) + (col & 7);
        }
    }
    ushort_t* Pl = Plds + wave * 1024;

    const int skey = tid >> 3;
    const int sdg  = tid & 7;
    const size_t kgbase = ((size_t)b * SEQ) * 512 + h * 64 + sdg * 8;
    const size_t vgbase = ((size_t)bh * 64) * 4096 + sdg * 8;
    const int l0 = skey * 64 + ((sdg ^ (skey & 7)) * 8);
    const int l1 = l0 + 32 * 64;

    fx4 oacc[4];
    oacc[0] = 0; oacc[1] = 0; oacc[2] = 0; oacc[3] = 0;
    float l[4] = {0.f, 0.f, 0.f, 0.f};

    for (int kt = 0; kt < 9; ++kt) {
        int ts = q0 - 256 + kt * 64;
        if (ts < 0 || ts >= SEQ) continue;

        __syncthreads();
        {
            usx8 k0v = *(const usx8*)(Kb + kgbase + (size_t)(ts + skey) * 512);
            usx8 k1v = *(const usx8*)(Kb + kgbase + (size_t)(ts + skey + 32) * 512);
            usx8 v0v = *(const usx8*)(Vt + vgbase + (size_t)skey * 4096 + ts);
            usx8 v1v = *(const usx8*)(Vt + vgbase + (size_t)(skey + 32) * 4096 + ts);
            *(usx8*)&Klds[l0] = k0v;
            *(usx8*)&Klds[l1] = k1v;
            *(usx8*)&Vlds[l0] = v0v;
            *(usx8*)&Vlds[l1] = v1v;
        }
        __syncthreads();

        fx4 sacc[4];
        sacc[0] = 0; sacc[1] = 0; sacc[2] = 0; sacc[3] = 0;
        #pragma unroll
        for (int ks = 0; ks < 2; ++ks) {
            bf16x8 a = ks ? qf1 : qf0;
            #pragma unroll
            for (int tn = 0; tn < 4; ++tn) {
                bf16x8 bk = *(const bf16x8*)&Klds[koff[ks][tn]];
                sacc[tn] = __builtin_amdgcn_mfma_f32_16x16x32_bf16(a, bk, sacc[tn], 0, 0, 0);
            }
        }

        float ps[4] = {0.f, 0.f, 0.f, 0.f};
        #pragma unroll
        for (int tn = 0; tn < 4; ++tn) {
            int kg = ts + tn * 16 + lm;
            #pragma unroll
            for (int r = 0; r < 4; ++r) {
                int qg = qw + quad * 4 + r;
                int dlt = kg - qg;
                float p = (dlt <= 256 && dlt >= -256) ? __expf(sacc[tn][r] * 0.125f) : 0.0f;
                ps[r] += p;
                Pl[pwoff[tn][r]] = f2b(p);
            }
        }
        #pragma unroll
        for (int r = 0; r < 4; ++r) {
            float v = ps[r];
            v += __shfl_xor(v, 1); v += __shfl_xor(v, 2);
            v += __shfl_xor(v, 4); v += __shfl_xor(v, 8);
            l[r] += v;
        }

        #pragma unroll
        for (int ks = 0; ks < 2; ++ks) {
            bf16x8 ap = *(const bf16x8*)&Pl[poff[ks]];
            #pragma unroll
            for (int tn = 0; tn < 4; ++tn) {
                bf16x8 bv = *(const bf16x8*)&Vlds[voff[ks][tn]];
                oacc[tn] = __builtin_amdgcn_mfma_f32_16x16x32_bf16(ap, bv, oacc[tn], 0, 0, 0);
            }
        }
    }

    #pragma unroll
    for (int r = 0; r < 4; ++r) l[r] = 1.0f / l[r];
    ushort_t* ob = Ob + ((size_t)(b * SEQ + qw + quad * 4)) * 512 + h * 64 + lm;
    #pragma unroll
    for (int tn = 0; tn < 4; ++tn) {
        #pragma unroll
        for (int r = 0; r < 4; ++r) {
            ob[(size_t)r * 512 + tn * 16] = f2b(oacc[tn][r] * l[r]);
        }
    }
}

// ---------------- residual + LayerNorm ----------------
__global__ __launch_bounds__(256) void ln_kernel(
    const float* __restrict__ x, const ushort_t* __restrict__ ob,
    const float* __restrict__ gamma, const float* __restrict__ beta,
    float* __restrict__ out) {

    int row  = blockIdx.x * 4 + (threadIdx.x >> 6);
    int lane = threadIdx.x & 63;

    const float*    xp = x  + (size_t)row * 512 + lane * 8;
    const ushort_t* op = ob + (size_t)row * 512 + lane * 8;

    fx4 xa = ((const fx4*)xp)[0];
    fx4 xb = ((const fx4*)xp)[1];
    usx4 oa = ((const usx4*)op)[0];
    usx4 oc = ((const usx4*)op)[1];
    fx4 va, vb;
    va.x = xa.x + b2f(oa.x); va.y = xa.y + b2f(oa.y); va.z = xa.z + b2f(oa.z); va.w = xa.w + b2f(oa.w);
    vb.x = xb.x + b2f(oc.x); vb.y = xb.y + b2f(oc.y); vb.z = xb.z + b2f(oc.z); vb.w = xb.w + b2f(oc.w);

    float s = va.x + va.y + va.z + va.w + vb.x + vb.y + vb.z + vb.w;
    #pragma unroll
    for (int m = 32; m > 0; m >>= 1) s += __shfl_xor(s, m);
    float mu = s * (1.0f / 512.0f);

    fx4 da = va - mu;
    fx4 db = vb - mu;
    float ss = da.x*da.x + da.y*da.y + da.z*da.z + da.w*da.w
             + db.x*db.x + db.y*db.y + db.z*db.z + db.w*db.w;
    #pragma unroll
    for (int m = 32; m > 0; m >>= 1) ss += __shfl_xor(ss, m);
    float rstd = rsqrtf(ss * (1.0f / 512.0f) + 1e-5f);

    const fx4* gp = (const fx4*)(gamma + lane * 8);
    const fx4* bp = (const fx4*)(beta  + lane * 8);
    fx4 g0 = gp[0], g1 = gp[1], b0 = bp[0], b1 = bp[1];

    float* outp = out + (size_t)row * 512 + lane * 8;
    fx4 r0 = da * rstd * g0 + b0;
    fx4 r1 = db * rstd * g1 + b1;
    ((fx4*)outp)[0] = r0;
    ((fx4*)outp)[1] = r1;
}

extern "C" void kernel_launch(void* const* d_in, const int* in_sizes, int n_in,
                              void* d_out, int out_size, void* d_ws, size_t ws_size,
                              hipStream_t stream) {
    const float* val   = (const float*)d_in[0];
    const float* Wq    = (const float*)d_in[1];
    const float* bq    = (const float*)d_in[2];
    const float* Wk    = (const float*)d_in[3];
    const float* bk    = (const float*)d_in[4];
    const float* Wv    = (const float*)d_in[5];
    const float* bv    = (const float*)d_in[6];
    const float* Wo    = (const float*)d_in[7];
    const float* bo    = (const float*)d_in[8];
    const float* gamma = (const float*)d_in[9];
    const float* beta  = (const float*)d_in[10];
    float* out = (float*)d_out;

    char* w = (char*)d_ws;
    ushort_t* xb    = (ushort_t*)w; w += (size_t)ROWS * 512 * 2;
    ushort_t* WqT   = (ushort_t*)w; w += 512 * 512 * 2;
    ushort_t* WkT   = (ushort_t*)w; w += 512 * 512 * 2;
    ushort_t* WvT   = (ushort_t*)w; w += 512 * 512 * 2;
    ushort_t* WoT   = (ushort_t*)w; w += 512 * 512 * 2;
    ushort_t* Qb    = (ushort_t*)w; w += (size_t)ROWS * 512 * 2;
    ushort_t* Kb    = (ushort_t*)w; w += (size_t)ROWS * 512 * 2;
    ushort_t* Vtb   = (ushort_t*)w; w += (size_t)ROWS * 512 * 2;   // [bh][d][s]
    ushort_t* attnb = (ushort_t*)w; w += (size_t)ROWS * 512 * 2;
    ushort_t* obuf  = (ushort_t*)w; w += (size_t)ROWS * 512 * 2;

    int nelem = ROWS * 512;
    cvt_bf16_kernel<<<nelem / (256 * 4), 256, 0, stream>>>(val, xb, nelem);
    transpose4_bf16_kernel<<<dim3(64, 4), 256, 0, stream>>>(
        Wq, Wk, Wv, Wo, WqT, WkT, WvT, WoT);

    gemm128_kernel<<<dim3(ROWS / 128, 4, 3), 256, 0, stream>>>(
        xb, WqT, WkT, WvT, bq, bk, bv, Qb, Kb, Vtb);

    attn_mfma_kernel<<<dim3(SEQ / 64, BATCH * NHEAD), 256, 0, stream>>>(Qb, Kb, Vtb, attnb);

    gemm128_kernel<<<dim3(ROWS / 128, 4, 1), 256, 0, stream>>>(
        attnb, WoT, WoT, WoT, bo, bo, bo, obuf, obuf, obuf);

    ln_kernel<<<ROWS / 4, 256, 0, stream>>>(val, obuf, gamma, beta, out);
}